// Round 3
// baseline (9974.000 us; speedup 1.0000x reference)
//
#include <hip/hip_runtime.h>
#include <cstdint>
#include <cstddef>

// ---------------- problem constants ----------------
#define SEQ    512
#define BATCH  128
#define EMB    512
#define HID    1024
#define KTOT   1536   // EMB + HID fused K
#define NOUT   8

// ---------------- decomposition ----------------
#define GN     128    // column-tile blocks over hidden units
#define UPB    8      // hidden units per block  (HID/GN)
#define NCOL   32     // gate columns per block  (4*UPB)
#define NBLK   256    // GN * GM, GM=2 batch halves
#define WPAD   1544   // padded K stride (elements) for LDS W
#define FSTR   16     // flag stride in u32 (64 B spacing)

typedef unsigned short u16;
typedef __attribute__((ext_vector_type(8))) __bf16 bf16x8;
typedef __attribute__((ext_vector_type(4))) float  f32x4;
typedef __attribute__((ext_vector_type(4))) float  float4v;
typedef __attribute__((ext_vector_type(4))) u16    u16x4;

// ---------------- workspace layout ----------------
#define OFF_X   0ull
#define SZ_X    ((size_t)SEQ*BATCH*EMB*2)      // 64 MB  bf16 x [S][B][E]
#define OFF_W   (OFF_X + SZ_X)
#define SZ_W    ((size_t)GN*NCOL*KTOT*2)       // 12 MB  bf16 packed weights
#define OFF_H0  (OFF_W + SZ_W)
#define SZ_H    ((size_t)BATCH*HID*2)          // 256 KB bf16 h buffer
#define OFF_H1  (OFF_H0 + SZ_H)
#define OFF_CNT (OFF_H1 + SZ_H)
#define SZ_CNT  ((size_t)NBLK*FSTR*4)          // 16 KB  per-block flags
#define WS_NEED (OFF_CNT + SZ_CNT)

#define SMEM_BYTES ((size_t)NCOL*WPAD*2 + 128)

// ---------------- helpers ----------------
__device__ inline u16 f2b(float f) {            // f32 -> bf16 RNE
  uint32_t u = __builtin_bit_cast(uint32_t, f);
  u = u + 0x7FFFu + ((u >> 16) & 1u);
  return (u16)(u >> 16);
}
__device__ inline float b2f(u16 u) {
  uint32_t v = ((uint32_t)u) << 16;
  return __builtin_bit_cast(float, v);
}
__device__ inline float sigm(float x) { return 1.0f / (1.0f + __expf(-x)); }
__device__ inline float tanh_(float x) {
  x = fminf(fmaxf(x, -15.f), 15.f);
  float e = __expf(2.f * x);
  return (e - 1.f) / (e + 1.f);
}
__device__ inline f32x4 mfma16(bf16x8 a, bf16x8 b, f32x4 c) {
  return __builtin_amdgcn_mfma_f32_16x16x32_bf16(a, b, c, 0, 0, 0);
}

// ---------------- prep: embedding gather -> bf16 x[t][b][e] ----------------
__global__ void embed_kernel(const int* __restrict__ ids,
                             const float* __restrict__ emb,
                             u16* __restrict__ x) {
  int bid = blockIdx.x;            // t*128 + b
  int t = bid >> 7, b = bid & 127;
  int idx = ids[b * SEQ + t];
  const float4v* src = (const float4v*)(emb + (size_t)idx * EMB);
  float4v v = src[threadIdx.x];    // 128 threads x float4 = 512 floats
  u16x4 o;
  o.x = f2b(v.x); o.y = f2b(v.y); o.z = f2b(v.z); o.w = f2b(v.w);
  *(u16x4*)(x + (size_t)bid * EMB + threadIdx.x * 4) = o;
}

// ---------------- prep: pack [W_ih | W_hh] rows, gate-reordered, bf16 --------
// Wr[n][c][k]: block n owns units j0=n*8..n*8+7; c = q*8+u -> row q*1024+n*8+u
__global__ void wpack_kernel(const float* __restrict__ Wih,
                             const float* __restrict__ Whh,
                             u16* __restrict__ Wr) {
  int bid = blockIdx.x;            // n*32 + c
  int c = bid & 31, n = bid >> 5;
  int q = c >> 3, u = c & 7;
  int row = q * HID + n * UPB + u;
  u16* dst = Wr + (size_t)bid * KTOT;
  for (int k = threadIdx.x; k < KTOT; k += 256) {
    float v = (k < EMB) ? Wih[(size_t)row * EMB + k]
                        : Whh[(size_t)row * HID + (k - EMB)];
    dst[k] = f2b(v);
  }
}

// ---------------- persistent LSTM recurrence ----------------
__global__ __launch_bounds__(256, 1) void lstm_kernel(
    const u16* __restrict__ x,     // [SEQ][BATCH][EMB] bf16
    const u16* __restrict__ Wr,    // [GN][NCOL][KTOT] bf16
    const float* __restrict__ bias,// [4*HID] f32
    u16* __restrict__ h0,          // [BATCH][HID] bf16 (holds h_last at end)
    u16* __restrict__ h1,          // double buffer B
    unsigned* __restrict__ flags)  // [NBLK*FSTR] per-block arrival flags (zeroed)
{
  extern __shared__ char smem[];
  u16* Wl = (u16*)smem;                      // [NCOL][WPAD]

  const int tid  = threadIdx.x;
  const int bid  = blockIdx.x;
  const int n    = bid & (GN - 1);   // column block
  const int mh   = bid >> 7;         // batch half 0/1
  const int lane = tid & 63;
  const int wid  = tid >> 6;         // 4 waves: m-tile id

  // ---- stage W into LDS (once) ----
  const u16* wsrc = Wr + (size_t)n * NCOL * KTOT;
  for (int e = tid * 8; e < NCOL * KTOT; e += 256 * 8) {
    int c = e / KTOT;
    int k = e - c * KTOT;
    *(bf16x8*)&Wl[c * WPAD + k] = *(const bf16x8*)&wsrc[e];
  }
  __syncthreads();

  // ---- MFMA fragment indexing ----
  const int arow = lane & 15;            // A row within 16-tile
  const int kl   = (lane >> 4) * 8;      // k sub-offset within 32-chunk
  const int bg   = mh * 64 + wid * 16 + arow;  // global batch row for A loads
  const int dcol = lane & 15;            // D col within 16-tile
  const int drow = (lane >> 4) * 4;      // D row base within 16-tile

  // ---- elementwise mapping: lane pair (l, l^8) shares unit u = lane&7 ----
  const int  u    = lane & 7;
  const bool lolane = (lane & 8) == 0;
  const int  colu = n * UPB + u;         // global hidden-unit column

  const float bi_ = bias[colu];
  const float bf_ = bias[HID + colu];
  const float bg_ = bias[2 * HID + colu];
  const float bo_ = bias[3 * HID + colu];

  const u16* w0p = &Wl[(dcol) * WPAD + kl];       // n-tile 0 (cols 0..15)
  const u16* w1p = &Wl[(16 + dcol) * WPAD + kl];  // n-tile 1 (cols 16..31)

  float cst[4] = {0.f, 0.f, 0.f, 0.f};   // cell state (redundant in lane pair)

  // ---- poll addresses: lane l watches flags for blocks l, 64+l, 128+l, 192+l
  const unsigned* f0p = &flags[(lane)       * FSTR];
  const unsigned* f1p = &flags[(64 + lane)  * FSTR];
  const unsigned* f2p = &flags[(128 + lane) * FSTR];
  const unsigned* f3p = &flags[(192 + lane) * FSTR];

  // ---- prologue: x fragments + x-part MFMAs for t=0 ----
  bf16x8 xfrag[16];
  {
    const u16* xr = x + ((size_t)bg) * EMB + kl;
    #pragma unroll
    for (int kc = 0; kc < 16; ++kc) xfrag[kc] = *(const bf16x8*)(xr + kc * 32);
  }
  f32x4 acc[2][2];
  #pragma unroll
  for (int i = 0; i < 2; ++i)
    #pragma unroll
    for (int j = 0; j < 2; ++j) acc[i][j] = (f32x4){0.f, 0.f, 0.f, 0.f};
  #pragma unroll
  for (int kc = 0; kc < 16; ++kc) {
    bf16x8 w0 = *(const bf16x8*)(w0p + kc * 32);
    bf16x8 w1 = *(const bf16x8*)(w1p + kc * 32);
    acc[kc & 1][0] = mfma16(xfrag[kc], w0, acc[kc & 1][0]);
    acc[kc & 1][1] = mfma16(xfrag[kc], w1, acc[kc & 1][1]);
  }

  #pragma unroll 1
  for (int t = 0; t < SEQ; ++t) {
    // ---- wait for h(t): all blocks' flags >= t (step t-1 arrivals) ----
    if (t > 0) {
      const unsigned tgt = (unsigned)t;
      for (;;) {
        unsigned a = __hip_atomic_load(f0p, __ATOMIC_RELAXED, __HIP_MEMORY_SCOPE_AGENT);
        unsigned b = __hip_atomic_load(f1p, __ATOMIC_RELAXED, __HIP_MEMORY_SCOPE_AGENT);
        unsigned c = __hip_atomic_load(f2p, __ATOMIC_RELAXED, __HIP_MEMORY_SCOPE_AGENT);
        unsigned d = __hip_atomic_load(f3p, __ATOMIC_RELAXED, __HIP_MEMORY_SCOPE_AGENT);
        bool ok = (a >= tgt) & (b >= tgt) & (c >= tgt) & (d >= tgt);
        if (__all(ok)) break;
        __builtin_amdgcn_s_sleep(1);
      }
      __builtin_amdgcn_fence(__ATOMIC_ACQUIRE, "agent");
    }

    const u16* hr_buf = (t & 1) ? h1 : h0;   // h(t)
    u16*       hw_buf = (t & 1) ? h0 : h1;   // h(t+1)
    const u16* hr = hr_buf + (size_t)bg * HID + kl;

    // ---- issue ALL h loads first: 32 x 16B in flight ----
    bf16x8 hfrag[32];
    #pragma unroll
    for (int kc = 0; kc < 32; ++kc) hfrag[kc] = *(const bf16x8*)(hr + kc * 32);

    // ---- prefetch x for t+1 (latency hides under h-MFMAs + barrier) ----
    {
      int tn = (t < SEQ - 1) ? (t + 1) : t;
      const u16* xr = x + ((size_t)tn * BATCH + bg) * EMB + kl;
      #pragma unroll
      for (int kc = 0; kc < 16; ++kc) xfrag[kc] = *(const bf16x8*)(xr + kc * 32);
    }

    // ---- h-part MFMAs (accumulate onto pre-computed x-part) ----
    #pragma unroll
    for (int kc = 0; kc < 32; ++kc) {
      bf16x8 w0 = *(const bf16x8*)(w0p + EMB + kc * 32);
      bf16x8 w1 = *(const bf16x8*)(w1p + EMB + kc * 32);
      acc[kc & 1][0] = mfma16(hfrag[kc], w0, acc[kc & 1][0]);
      acc[kc & 1][1] = mfma16(hfrag[kc], w1, acc[kc & 1][1]);
    }

    // ---- gates: tile0 = {i,f}, tile1 = {g,o}; lane^8 holds the partner ----
    f32x4 g0, g1;
    #pragma unroll
    for (int r = 0; r < 4; ++r) {
      g0[r] = acc[0][0][r] + acc[1][0][r];
      g1[r] = acc[0][1][r] + acc[1][1][r];
    }
    f32x4 p0, p1;
    #pragma unroll
    for (int r = 0; r < 4; ++r) {
      p0[r] = __shfl_xor(g0[r], 8);
      p1[r] = __shfl_xor(g1[r], 8);
    }

    #pragma unroll
    for (int r = 0; r < 4; ++r) {
      float iv = (lolane ? g0[r] : p0[r]) + bi_;
      float fv = (lolane ? p0[r] : g0[r]) + bf_;
      float gv = (lolane ? g1[r] : p1[r]) + bg_;
      float ov = (lolane ? p1[r] : g1[r]) + bo_;
      float cn = sigm(fv) * cst[r] + sigm(iv) * tanh_(gv);
      cst[r] = cn;
      float hv = sigm(ov) * tanh_(cn);
      // lane pair computes identical values; split the 4 row-stores
      if (lolane ? (r < 2) : (r >= 2))
        hw_buf[(size_t)(mh * 64 + wid * 16 + drow + r) * HID + colu] = f2b(hv);
    }

    // ---- arrive: all waves' stores drained, then release-store own flag ----
    __syncthreads();   // per-wave vmcnt(0) before s_barrier: h stores drained
    if (tid == 0) {
      __builtin_amdgcn_fence(__ATOMIC_RELEASE, "agent");
      __hip_atomic_store(&flags[bid * FSTR], (unsigned)(t + 1),
                         __ATOMIC_RELAXED, __HIP_MEMORY_SCOPE_AGENT);
    }

    // ---- barrier window: x-part MFMAs for t+1 (no cross-block dependency) --
    #pragma unroll
    for (int i = 0; i < 2; ++i)
      #pragma unroll
      for (int j = 0; j < 2; ++j) acc[i][j] = (f32x4){0.f, 0.f, 0.f, 0.f};
    #pragma unroll
    for (int kc = 0; kc < 16; ++kc) {
      bf16x8 w0 = *(const bf16x8*)(w0p + kc * 32);
      bf16x8 w1 = *(const bf16x8*)(w1p + kc * 32);
      acc[kc & 1][0] = mfma16(xfrag[kc], w0, acc[kc & 1][0]);
      acc[kc & 1][1] = mfma16(xfrag[kc], w1, acc[kc & 1][1]);
    }
    __builtin_amdgcn_sched_barrier(0);  // keep x-MFMAs before the next poll
  }
}

// ---------------- classifier head: out = h_last @ W_out^T + b_out ----------
__global__ void head_kernel(const u16* __restrict__ h,
                            const float* __restrict__ Wout,
                            const float* __restrict__ bout,
                            float* __restrict__ out) {
  int b = blockIdx.x, l = threadIdx.x;
  float p[NOUT];
  #pragma unroll
  for (int o = 0; o < NOUT; ++o) p[o] = 0.f;
  for (int k = l; k < HID; k += 64) {
    float hv = b2f(h[(size_t)b * HID + k]);
    #pragma unroll
    for (int o = 0; o < NOUT; ++o) p[o] += hv * Wout[(size_t)o * HID + k];
  }
  #pragma unroll
  for (int o = 0; o < NOUT; ++o) {
    float v = p[o];
    #pragma unroll
    for (int off = 32; off > 0; off >>= 1) v += __shfl_down(v, off);
    if (l == 0) out[b * NOUT + o] = v + bout[o];
  }
}

// sentinel if workspace too small (distinguishable absmax ~1e9)
__global__ void sentinel_kernel(float* out, int n) {
  int i = blockIdx.x * 256 + threadIdx.x;
  if (i < n) out[i] = 1e9f;
}

extern "C" void kernel_launch(void* const* d_in, const int* in_sizes, int n_in,
                              void* d_out, int out_size, void* d_ws, size_t ws_size,
                              hipStream_t stream) {
  const int*   ids  = (const int*)d_in[0];
  const float* emb  = (const float*)d_in[1];
  const float* Wih  = (const float*)d_in[2];
  const float* Whh  = (const float*)d_in[3];
  const float* bias = (const float*)d_in[4];
  const float* Wout = (const float*)d_in[5];
  const float* bout = (const float*)d_in[6];
  float* out = (float*)d_out;

  if (ws_size < WS_NEED) {
    sentinel_kernel<<<(out_size + 255) / 256, 256, 0, stream>>>(out, out_size);
    return;
  }

  char* ws = (char*)d_ws;
  u16*      x   = (u16*)(ws + OFF_X);
  u16*      Wr  = (u16*)(ws + OFF_W);
  u16*      h0  = (u16*)(ws + OFF_H0);
  u16*      h1  = (u16*)(ws + OFF_H1);
  unsigned* flg = (unsigned*)(ws + OFF_CNT);

  hipMemsetAsync(h0, 0, SZ_H, stream);       // h_0 = 0
  hipMemsetAsync(flg, 0, SZ_CNT, stream);    // arrival flags (every call!)

  embed_kernel<<<SEQ * BATCH, 128, 0, stream>>>(ids, emb, x);
  wpack_kernel<<<GN * NCOL, 256, 0, stream>>>(Wih, Whh, Wr);

  hipFuncSetAttribute((const void*)lstm_kernel,
                      hipFuncAttributeMaxDynamicSharedMemorySize,
                      (int)SMEM_BYTES);
  lstm_kernel<<<NBLK, 256, SMEM_BYTES, stream>>>(x, Wr, bias, h0, h1, flg);

  // after 512 steps (even), h_last lives in h0
  head_kernel<<<BATCH, 64, 0, stream>>>(h0, Wout, bout, out);
}

// Round 4
// 8609.097 us; speedup vs baseline: 1.1585x; 1.1585x over previous
//
#include <hip/hip_runtime.h>
#include <cstdint>
#include <cstddef>

// ---------------- problem constants ----------------
#define SEQ    512
#define BATCH  128
#define EMB    512
#define HID    1024
#define KTOT   1536   // EMB + HID fused K
#define NOUT   8

// ---------------- decomposition ----------------
#define GN     128    // column-tile blocks over hidden units
#define UPB    8      // hidden units per block  (HID/GN)
#define NCOL   32     // gate columns per block  (4*UPB)
#define NBLK   256    // GN * GM, GM=2 batch halves
#define WPAD   1544   // padded K stride (elements) for LDS W
#define NGRP   8      // barrier tree fan-in groups (aligned to XCD round-robin)
#define GRPSZ  (NBLK/NGRP)   // 32 blocks per group

typedef unsigned short u16;
typedef __attribute__((ext_vector_type(8))) __bf16 bf16x8;
typedef __attribute__((ext_vector_type(4))) float  f32x4;
typedef __attribute__((ext_vector_type(4))) float  float4v;
typedef __attribute__((ext_vector_type(4))) u16    u16x4;

// ---------------- workspace layout ----------------
#define OFF_X    0ull
#define SZ_X     ((size_t)SEQ*BATCH*EMB*2)      // 64 MB  bf16 x [S][B][E]
#define OFF_W    (OFF_X + SZ_X)
#define SZ_W     ((size_t)GN*NCOL*KTOT*2)       // 12 MB  bf16 packed weights
#define OFF_H0   (OFF_W + SZ_W)
#define SZ_H     ((size_t)BATCH*HID*2)          // 256 KB bf16 h buffer
#define OFF_H1   (OFF_H0 + SZ_H)
#define OFF_SYNC (OFF_H1 + SZ_H)
#define SZ_ROOT  ((size_t)SEQ*16*4)             // 32 KB  root[t], 64B-spaced
#define SZ_GRP   ((size_t)SEQ*NGRP*16*4)        // 256 KB grp[t][g], 64B-spaced
#define SZ_SYNC  (SZ_ROOT + SZ_GRP)
#define WS_NEED  (OFF_SYNC + SZ_SYNC)

#define SMEM_BYTES ((size_t)NCOL*WPAD*2 + 128)

// ---------------- helpers ----------------
__device__ inline u16 f2b(float f) {            // f32 -> bf16 RNE
  uint32_t u = __builtin_bit_cast(uint32_t, f);
  u = u + 0x7FFFu + ((u >> 16) & 1u);
  return (u16)(u >> 16);
}
__device__ inline float b2f(u16 u) {
  uint32_t v = ((uint32_t)u) << 16;
  return __builtin_bit_cast(float, v);
}
__device__ inline float sigm(float x) { return 1.0f / (1.0f + __expf(-x)); }
__device__ inline float tanh_(float x) {
  x = fminf(fmaxf(x, -15.f), 15.f);
  float e = __expf(2.f * x);
  return (e - 1.f) / (e + 1.f);
}
__device__ inline f32x4 mfma16(bf16x8 a, bf16x8 b, f32x4 c) {
  return __builtin_amdgcn_mfma_f32_16x16x32_bf16(a, b, c, 0, 0, 0);
}

// ---------------- prep: embedding gather -> bf16 x[t][b][e] ----------------
__global__ void embed_kernel(const int* __restrict__ ids,
                             const float* __restrict__ emb,
                             u16* __restrict__ x) {
  int bid = blockIdx.x;            // t*128 + b
  int t = bid >> 7, b = bid & 127;
  int idx = ids[b * SEQ + t];
  const float4v* src = (const float4v*)(emb + (size_t)idx * EMB);
  float4v v = src[threadIdx.x];    // 128 threads x float4 = 512 floats
  u16x4 o;
  o.x = f2b(v.x); o.y = f2b(v.y); o.z = f2b(v.z); o.w = f2b(v.w);
  *(u16x4*)(x + (size_t)bid * EMB + threadIdx.x * 4) = o;
}

// ---------------- prep: pack [W_ih | W_hh] rows, gate-reordered, bf16 --------
// Wr[n][c][k]: block n owns units j0=n*8..n*8+7; c = q*8+u -> row q*1024+n*8+u
__global__ void wpack_kernel(const float* __restrict__ Wih,
                             const float* __restrict__ Whh,
                             u16* __restrict__ Wr) {
  int bid = blockIdx.x;            // n*32 + c
  int c = bid & 31, n = bid >> 5;
  int q = c >> 3, u = c & 7;
  int row = q * HID + n * UPB + u;
  u16* dst = Wr + (size_t)bid * KTOT;
  for (int k = threadIdx.x; k < KTOT; k += 256) {
    float v = (k < EMB) ? Wih[(size_t)row * EMB + k]
                        : Whh[(size_t)row * HID + (k - EMB)];
    dst[k] = f2b(v);
  }
}

// ---------------- persistent LSTM recurrence ----------------
__global__ __launch_bounds__(256, 1) void lstm_kernel(
    const u16* __restrict__ x,     // [SEQ][BATCH][EMB] bf16
    const u16* __restrict__ Wr,    // [GN][NCOL][KTOT] bf16
    const float* __restrict__ bias,// [4*HID] f32
    u16* __restrict__ h0,          // [BATCH][HID] bf16 (holds h_last at end)
    u16* __restrict__ h1,          // double buffer B
    unsigned* __restrict__ root,   // [SEQ] root counters, 64B-spaced (zeroed)
    unsigned* __restrict__ grp)    // [SEQ][NGRP] group counters, 64B-spaced (zeroed)
{
  extern __shared__ char smem[];
  u16* Wl = (u16*)smem;                      // [NCOL][WPAD]

  const int tid  = threadIdx.x;
  const int bid  = blockIdx.x;
  const int n    = bid & (GN - 1);   // column block
  const int mh   = bid >> 7;         // batch half 0/1
  const int lane = tid & 63;
  const int wid  = tid >> 6;         // 4 waves: m-tile id

  // ---- stage W into LDS (once) ----
  const u16* wsrc = Wr + (size_t)n * NCOL * KTOT;
  for (int e = tid * 8; e < NCOL * KTOT; e += 256 * 8) {
    int c = e / KTOT;
    int k = e - c * KTOT;
    *(bf16x8*)&Wl[c * WPAD + k] = *(const bf16x8*)&wsrc[e];
  }
  __syncthreads();

  // ---- MFMA fragment indexing ----
  const int arow = lane & 15;            // A row within 16-tile
  const int kl   = (lane >> 4) * 8;      // k sub-offset within 32-chunk
  const int bg   = mh * 64 + wid * 16 + arow;  // global batch row for A loads
  const int dcol = lane & 15;            // D col within 16-tile
  const int drow = (lane >> 4) * 4;      // D row base within 16-tile

  // ---- elementwise mapping: lane pair (l, l^8) shares unit u = lane&7 ----
  const int  u    = lane & 7;
  const bool lolane = (lane & 8) == 0;
  const int  colu = n * UPB + u;         // global hidden-unit column

  const float bi_ = bias[colu];
  const float bf_ = bias[HID + colu];
  const float bg_ = bias[2 * HID + colu];
  const float bo_ = bias[3 * HID + colu];

  const u16* w0p = &Wl[(dcol) * WPAD + kl];       // n-tile 0 (cols 0..15)
  const u16* w1p = &Wl[(16 + dcol) * WPAD + kl];  // n-tile 1 (cols 16..31)

  float cst[4] = {0.f, 0.f, 0.f, 0.f};   // cell state (redundant in lane pair)

  // ---- prefetch x fragments for t=0 ----
  bf16x8 xfrag[16];
  {
    const u16* xr = x + ((size_t)bg) * EMB + kl;
    #pragma unroll
    for (int kc = 0; kc < 16; ++kc) xfrag[kc] = *(const bf16x8*)(xr + kc * 32);
  }

  #pragma unroll 1
  for (int t = 0; t < SEQ; ++t) {
    const u16* hr_buf = (t & 1) ? h1 : h0;
    u16*       hw_buf = (t & 1) ? h0 : h1;
    const u16* hr = hr_buf + (size_t)bg * HID + kl;

    // ---- issue ALL h loads first: 32 x 16B in flight ----
    bf16x8 hfrag[32];
    #pragma unroll
    for (int kc = 0; kc < 32; ++kc) hfrag[kc] = *(const bf16x8*)(hr + kc * 32);

    f32x4 acc[2][2];
    #pragma unroll
    for (int i = 0; i < 2; ++i)
      #pragma unroll
      for (int j = 0; j < 2; ++j) acc[i][j] = (f32x4){0.f, 0.f, 0.f, 0.f};

    // ---- x-part MFMAs (independent of h: overlaps h-load latency) ----
    #pragma unroll
    for (int kc = 0; kc < 16; ++kc) {
      bf16x8 w0 = *(const bf16x8*)(w0p + kc * 32);
      bf16x8 w1 = *(const bf16x8*)(w1p + kc * 32);
      acc[kc & 1][0] = mfma16(xfrag[kc], w0, acc[kc & 1][0]);
      acc[kc & 1][1] = mfma16(xfrag[kc], w1, acc[kc & 1][1]);
    }

    // ---- prefetch x for t+1 (completes during h-MFMAs / barrier) ----
    if (t < SEQ - 1) {
      const u16* xr = x + ((size_t)(t + 1) * BATCH + bg) * EMB + kl;
      #pragma unroll
      for (int kc = 0; kc < 16; ++kc) xfrag[kc] = *(const bf16x8*)(xr + kc * 32);
    }

    // ---- h-part MFMAs ----
    #pragma unroll
    for (int kc = 0; kc < 32; ++kc) {
      bf16x8 w0 = *(const bf16x8*)(w0p + EMB + kc * 32);
      bf16x8 w1 = *(const bf16x8*)(w1p + EMB + kc * 32);
      acc[kc & 1][0] = mfma16(hfrag[kc], w0, acc[kc & 1][0]);
      acc[kc & 1][1] = mfma16(hfrag[kc], w1, acc[kc & 1][1]);
    }

    // ---- gates: tile0 = {i,f}, tile1 = {g,o}; lane^8 holds the partner ----
    f32x4 g0, g1;
    #pragma unroll
    for (int r = 0; r < 4; ++r) {
      g0[r] = acc[0][0][r] + acc[1][0][r];
      g1[r] = acc[0][1][r] + acc[1][1][r];
    }
    f32x4 p0, p1;
    #pragma unroll
    for (int r = 0; r < 4; ++r) {
      p0[r] = __shfl_xor(g0[r], 8);
      p1[r] = __shfl_xor(g1[r], 8);
    }

    #pragma unroll
    for (int r = 0; r < 4; ++r) {
      float iv = (lolane ? g0[r] : p0[r]) + bi_;
      float fv = (lolane ? p0[r] : g0[r]) + bf_;
      float gv = (lolane ? g1[r] : p1[r]) + bg_;
      float ov = (lolane ? p1[r] : g1[r]) + bo_;
      float cn = sigm(fv) * cst[r] + sigm(iv) * tanh_(gv);
      cst[r] = cn;
      float hv = sigm(ov) * tanh_(cn);
      // lane pair computes identical values; split the 4 row-stores
      if (lolane ? (r < 2) : (r >= 2))
        hw_buf[(size_t)(mh * 64 + wid * 16 + drow + r) * HID + colu] = f2b(hv);
    }

    // ---- tree barrier: grp (32 RMWs, no readers) -> root (8 RMWs, polled) --
    __syncthreads();   // per-wave vmcnt(0) before s_barrier: h stores drained
    if (tid == 0) {
      unsigned* gcnt = &grp[((size_t)t * NGRP + (bid & (NGRP - 1))) * 16];
      unsigned* rcnt = &root[(size_t)t * 16];
      __builtin_amdgcn_fence(__ATOMIC_RELEASE, "agent");
      unsigned old = __hip_atomic_fetch_add(gcnt, 1u, __ATOMIC_ACQ_REL,
                                            __HIP_MEMORY_SCOPE_AGENT);
      if (old == (unsigned)(GRPSZ - 1)) {
        __hip_atomic_fetch_add(rcnt, 1u, __ATOMIC_RELEASE,
                               __HIP_MEMORY_SCOPE_AGENT);
      }
      while (__hip_atomic_load(rcnt, __ATOMIC_RELAXED,
                               __HIP_MEMORY_SCOPE_AGENT) < (unsigned)NGRP) {
        __builtin_amdgcn_s_sleep(1);
      }
      __builtin_amdgcn_fence(__ATOMIC_ACQUIRE, "agent");
    }
    __syncthreads();
  }
}

// ---------------- classifier head: out = h_last @ W_out^T + b_out ----------
__global__ void head_kernel(const u16* __restrict__ h,
                            const float* __restrict__ Wout,
                            const float* __restrict__ bout,
                            float* __restrict__ out) {
  int b = blockIdx.x, l = threadIdx.x;
  float p[NOUT];
  #pragma unroll
  for (int o = 0; o < NOUT; ++o) p[o] = 0.f;
  for (int k = l; k < HID; k += 64) {
    float hv = b2f(h[(size_t)b * HID + k]);
    #pragma unroll
    for (int o = 0; o < NOUT; ++o) p[o] += hv * Wout[(size_t)o * HID + k];
  }
  #pragma unroll
  for (int o = 0; o < NOUT; ++o) {
    float v = p[o];
    #pragma unroll
    for (int off = 32; off > 0; off >>= 1) v += __shfl_down(v, off);
    if (l == 0) out[b * NOUT + o] = v + bout[o];
  }
}

// sentinel if workspace too small (distinguishable absmax ~1e9)
__global__ void sentinel_kernel(float* out, int n) {
  int i = blockIdx.x * 256 + threadIdx.x;
  if (i < n) out[i] = 1e9f;
}

extern "C" void kernel_launch(void* const* d_in, const int* in_sizes, int n_in,
                              void* d_out, int out_size, void* d_ws, size_t ws_size,
                              hipStream_t stream) {
  const int*   ids  = (const int*)d_in[0];
  const float* emb  = (const float*)d_in[1];
  const float* Wih  = (const float*)d_in[2];
  const float* Whh  = (const float*)d_in[3];
  const float* bias = (const float*)d_in[4];
  const float* Wout = (const float*)d_in[5];
  const float* bout = (const float*)d_in[6];
  float* out = (float*)d_out;

  if (ws_size < WS_NEED) {
    sentinel_kernel<<<(out_size + 255) / 256, 256, 0, stream>>>(out, out_size);
    return;
  }

  char* ws = (char*)d_ws;
  u16*      x    = (u16*)(ws + OFF_X);
  u16*      Wr   = (u16*)(ws + OFF_W);
  u16*      h0   = (u16*)(ws + OFF_H0);
  u16*      h1   = (u16*)(ws + OFF_H1);
  unsigned* root = (unsigned*)(ws + OFF_SYNC);
  unsigned* grp  = (unsigned*)(ws + OFF_SYNC + SZ_ROOT);

  hipMemsetAsync(h0, 0, SZ_H, stream);          // h_0 = 0
  hipMemsetAsync(root, 0, SZ_SYNC, stream);     // barrier counters (every call!)

  embed_kernel<<<SEQ * BATCH, 128, 0, stream>>>(ids, emb, x);
  wpack_kernel<<<GN * NCOL, 256, 0, stream>>>(Wih, Whh, Wr);

  hipFuncSetAttribute((const void*)lstm_kernel,
                      hipFuncAttributeMaxDynamicSharedMemorySize,
                      (int)SMEM_BYTES);
  lstm_kernel<<<NBLK, 256, SMEM_BYTES, stream>>>(x, Wr, bias, h0, h1, root, grp);

  // after 512 steps (even), h_last lives in h0
  head_kernel<<<BATCH, 64, 0, stream>>>(h0, Wout, bout, out);
}

// Round 5
// 6894.040 us; speedup vs baseline: 1.4468x; 1.2488x over previous
//
#include <hip/hip_runtime.h>
#include <cstdint>
#include <cstddef>

// ---------------- problem constants ----------------
#define SEQ    512
#define BATCH  128
#define EMB    512
#define HID    1024
#define KTOT   1536   // EMB + HID fused K
#define NOUT   8

// ---------------- decomposition ----------------
#define GN     128    // column-tile blocks over hidden units
#define UPB    8      // hidden units per block  (HID/GN)
#define NCOL   32     // gate columns per block  (4*UPB)
#define NBLK   256    // GN * GM, GM=2 batch halves
#define WPAD   1544   // padded K stride (elements) for LDS W

typedef unsigned short u16;
typedef unsigned int   u32;
typedef unsigned long long u64;
typedef __attribute__((ext_vector_type(8))) __bf16 bf16x8;
typedef __attribute__((ext_vector_type(4))) float  f32x4;
typedef __attribute__((ext_vector_type(4))) float  float4v;
typedef __attribute__((ext_vector_type(4))) u16    u16x4;

// ---------------- workspace layout ----------------
#define OFF_X    0ull
#define SZ_X     ((size_t)SEQ*BATCH*EMB*2)      // 64 MB  bf16 x [S][B][E]
#define OFF_W    (OFF_X + SZ_X)
#define SZ_W     ((size_t)GN*NCOL*KTOT*2)       // 12 MB  bf16 packed weights
#define OFF_H0   (OFF_W + SZ_W)
#define SZ_H     ((size_t)BATCH*HID*2)          // 256 KB bf16 h buffer
#define OFF_H1   (OFF_H0 + SZ_H)
#define OFF_CNT  (OFF_H1 + SZ_H)
#define SZ_CNT   ((size_t)SEQ*16*4)             // 32 KB  cnt[t], 64B-spaced
#define WS_NEED  (OFF_CNT + SZ_CNT)

#define SMEM_BYTES ((size_t)NCOL*WPAD*2 + 128)

// ---------------- helpers ----------------
__device__ inline u16 f2b(float f) {            // f32 -> bf16 RNE
  uint32_t u = __builtin_bit_cast(uint32_t, f);
  u = u + 0x7FFFu + ((u >> 16) & 1u);
  return (u16)(u >> 16);
}
__device__ inline float b2f(u16 u) {
  uint32_t v = ((uint32_t)u) << 16;
  return __builtin_bit_cast(float, v);
}
__device__ inline float sigm(float x) { return 1.0f / (1.0f + __expf(-x)); }
__device__ inline float tanh_(float x) {
  x = fminf(fmaxf(x, -15.f), 15.f);
  float e = __expf(2.f * x);
  return (e - 1.f) / (e + 1.f);
}
__device__ inline f32x4 mfma16(bf16x8 a, bf16x8 b, f32x4 c) {
  return __builtin_amdgcn_mfma_f32_16x16x32_bf16(a, b, c, 0, 0, 0);
}
struct QQ { u64 x, y; };
__device__ inline bf16x8 qq2v(u64 lo, u64 hi) {
  QQ q; q.x = lo; q.y = hi;
  return __builtin_bit_cast(bf16x8, q);
}

// ---------------- prep: embedding gather -> bf16 x[t][b][e] ----------------
__global__ void embed_kernel(const int* __restrict__ ids,
                             const float* __restrict__ emb,
                             u16* __restrict__ x) {
  int bid = blockIdx.x;            // t*128 + b
  int t = bid >> 7, b = bid & 127;
  int idx = ids[b * SEQ + t];
  const float4v* src = (const float4v*)(emb + (size_t)idx * EMB);
  float4v v = src[threadIdx.x];    // 128 threads x float4 = 512 floats
  u16x4 o;
  o.x = f2b(v.x); o.y = f2b(v.y); o.z = f2b(v.z); o.w = f2b(v.w);
  *(u16x4*)(x + (size_t)bid * EMB + threadIdx.x * 4) = o;
}

// ---------------- prep: pack [W_ih | W_hh] rows, gate-reordered, bf16 --------
// Wr[n][c][k]: block n owns units j0=n*8..n*8+7; c = q*8+u -> row q*1024+n*8+u
__global__ void wpack_kernel(const float* __restrict__ Wih,
                             const float* __restrict__ Whh,
                             u16* __restrict__ Wr) {
  int bid = blockIdx.x;            // n*32 + c
  int c = bid & 31, n = bid >> 5;
  int q = c >> 3, u = c & 7;
  int row = q * HID + n * UPB + u;
  u16* dst = Wr + (size_t)bid * KTOT;
  for (int k = threadIdx.x; k < KTOT; k += 256) {
    float v = (k < EMB) ? Wih[(size_t)row * EMB + k]
                        : Whh[(size_t)row * HID + (k - EMB)];
    dst[k] = f2b(v);
  }
}

// ---------------- persistent LSTM recurrence (fence-free sc1 exchange) ------
__global__ __launch_bounds__(256, 1) void lstm_kernel(
    const u16* __restrict__ x,     // [SEQ][BATCH][EMB] bf16
    const u16* __restrict__ Wr,    // [GN][NCOL][KTOT] bf16
    const float* __restrict__ bias,// [4*HID] f32
    u16* __restrict__ h0,          // [BATCH][HID] bf16 (holds h_last at end)
    u16* __restrict__ h1,          // double buffer B
    u32* __restrict__ cnt)         // [SEQ][16] barrier counters (zeroed)
{
  extern __shared__ char smem[];
  u16* Wl = (u16*)smem;                      // [NCOL][WPAD]

  const int tid  = threadIdx.x;
  const int bid  = blockIdx.x;
  const int n    = bid & (GN - 1);   // column block
  const int mh   = bid >> 7;         // batch half 0/1
  const int lane = tid & 63;
  const int wid  = tid >> 6;         // 4 waves: m-tile id

  // ---- stage W into LDS (once) ----
  const u16* wsrc = Wr + (size_t)n * NCOL * KTOT;
  for (int e = tid * 8; e < NCOL * KTOT; e += 256 * 8) {
    int c = e / KTOT;
    int k = e - c * KTOT;
    *(bf16x8*)&Wl[c * WPAD + k] = *(const bf16x8*)&wsrc[e];
  }
  __syncthreads();

  // ---- MFMA fragment indexing ----
  const int arow = lane & 15;            // A row within 16-tile
  const int kl   = (lane >> 4) * 8;      // k sub-offset within 32-chunk
  const int bg   = mh * 64 + wid * 16 + arow;  // global batch row for A loads
  const int dcol = lane & 15;            // D col within 16-tile
  const int drow = (lane >> 4) * 4;      // D row base within 16-tile

  // ---- elementwise mapping: lane pair (l, l^8) shares unit u = lane&7 ----
  const int  u    = lane & 7;
  const bool lolane = (lane & 8) == 0;
  const int  colu = n * UPB + u;         // global hidden-unit column

  const float bi_ = bias[colu];
  const float bf_ = bias[HID + colu];
  const float bg_ = bias[2 * HID + colu];
  const float bo_ = bias[3 * HID + colu];

  const u16* w0p = &Wl[(dcol) * WPAD + kl];       // n-tile 0 (cols 0..15)
  const u16* w1p = &Wl[(16 + dcol) * WPAD + kl];  // n-tile 1 (cols 16..31)

  float cst[4] = {0.f, 0.f, 0.f, 0.f};   // cell state (redundant in lane pair)

  // ---- prefetch x fragments for t=0 ----
  bf16x8 xfrag[16];
  {
    const u16* xr = x + ((size_t)bg) * EMB + kl;
    #pragma unroll
    for (int kc = 0; kc < 16; ++kc) xfrag[kc] = *(const bf16x8*)(xr + kc * 32);
  }

  #pragma unroll 1
  for (int t = 0; t < SEQ; ++t) {
    const u16* hr_buf = (t & 1) ? h1 : h0;
    u16*       hw_buf = (t & 1) ? h0 : h1;
    const u64* hq = (const u64*)(hr_buf + (size_t)bg * HID + kl);

    // ---- issue ALL h loads first: 64 x 8B sc1 loads in flight (bypass L2) --
    bf16x8 hfrag[32];
    if (t > 0) {
      #pragma unroll
      for (int kc = 0; kc < 32; ++kc) {
        u64 lo = __hip_atomic_load((const u64*)(hq + kc * 8),
                                   __ATOMIC_RELAXED, __HIP_MEMORY_SCOPE_AGENT);
        u64 hi = __hip_atomic_load((const u64*)(hq + kc * 8 + 1),
                                   __ATOMIC_RELAXED, __HIP_MEMORY_SCOPE_AGENT);
        hfrag[kc] = qq2v(lo, hi);
      }
    }

    f32x4 acc[2][2];
    #pragma unroll
    for (int i = 0; i < 2; ++i)
      #pragma unroll
      for (int j = 0; j < 2; ++j) acc[i][j] = (f32x4){0.f, 0.f, 0.f, 0.f};

    // ---- x-part MFMAs (independent of h: overlaps h-load latency) ----
    #pragma unroll
    for (int kc = 0; kc < 16; ++kc) {
      bf16x8 w0 = *(const bf16x8*)(w0p + kc * 32);
      bf16x8 w1 = *(const bf16x8*)(w1p + kc * 32);
      acc[kc & 1][0] = mfma16(xfrag[kc], w0, acc[kc & 1][0]);
      acc[kc & 1][1] = mfma16(xfrag[kc], w1, acc[kc & 1][1]);
    }

    // ---- prefetch x for t+1 (completes during h-MFMAs / barrier) ----
    if (t < SEQ - 1) {
      const u16* xr = x + ((size_t)(t + 1) * BATCH + bg) * EMB + kl;
      #pragma unroll
      for (int kc = 0; kc < 16; ++kc) xfrag[kc] = *(const bf16x8*)(xr + kc * 32);
    }

    // ---- h-part MFMAs ----
    if (t > 0) {
      #pragma unroll
      for (int kc = 0; kc < 32; ++kc) {
        bf16x8 w0 = *(const bf16x8*)(w0p + EMB + kc * 32);
        bf16x8 w1 = *(const bf16x8*)(w1p + EMB + kc * 32);
        acc[kc & 1][0] = mfma16(hfrag[kc], w0, acc[kc & 1][0]);
        acc[kc & 1][1] = mfma16(hfrag[kc], w1, acc[kc & 1][1]);
      }
    }

    // ---- gates: tile0 = {i,f}, tile1 = {g,o}; lane^8 holds the partner ----
    f32x4 g0, g1;
    #pragma unroll
    for (int r = 0; r < 4; ++r) {
      g0[r] = acc[0][0][r] + acc[1][0][r];
      g1[r] = acc[0][1][r] + acc[1][1][r];
    }
    f32x4 p0, p1;
    #pragma unroll
    for (int r = 0; r < 4; ++r) {
      p0[r] = __shfl_xor(g0[r], 8);
      p1[r] = __shfl_xor(g1[r], 8);
    }

    float hv4[4];
    #pragma unroll
    for (int r = 0; r < 4; ++r) {
      float iv = (lolane ? g0[r] : p0[r]) + bi_;
      float fv = (lolane ? p0[r] : g0[r]) + bf_;
      float gv = (lolane ? g1[r] : p1[r]) + bg_;
      float ov = (lolane ? p1[r] : g1[r]) + bo_;
      float cn = sigm(fv) * cst[r] + sigm(iv) * tanh_(gv);
      cst[r] = cn;
      hv4[r] = sigm(ov) * tanh_(cn);
    }

    // ---- h stores: pack 2 bf16 via lane^1, write-through u32 sc1 ----
    #pragma unroll
    for (int r = 0; r < 4; ++r) {
      float other = __shfl_xor(hv4[r], 1);          // col partner (u^1)
      bool doStore = (lolane ? (r < 2) : (r >= 2)) && ((u & 1) == 0);
      if (doStore) {
        u32 val = (u32)f2b(hv4[r]) | ((u32)f2b(other) << 16);
        u32* dst = (u32*)&hw_buf[(size_t)(mh * 64 + wid * 16 + drow + r) * HID + colu];
        __hip_atomic_store(dst, val, __ATOMIC_RELAXED, __HIP_MEMORY_SCOPE_AGENT);
      }
    }

    // ---- fence-free barrier: stores acked by vmcnt(0) in syncthreads ----
    __syncthreads();
    if (t == SEQ - 1) break;
    if (tid == 0) {
      __asm__ __volatile__("" ::: "memory");
      u32* c = &cnt[(size_t)t * 16];
      __hip_atomic_fetch_add(c, 1u, __ATOMIC_RELAXED, __HIP_MEMORY_SCOPE_AGENT);
      while (__hip_atomic_load(c, __ATOMIC_RELAXED, __HIP_MEMORY_SCOPE_AGENT)
             < (u32)NBLK) {
        __builtin_amdgcn_s_sleep(1);
      }
      __asm__ __volatile__("" ::: "memory");
    }
    __syncthreads();
  }
}

// ---------------- classifier head: out = h_last @ W_out^T + b_out ----------
__global__ void head_kernel(const u16* __restrict__ h,
                            const float* __restrict__ Wout,
                            const float* __restrict__ bout,
                            float* __restrict__ out) {
  int b = blockIdx.x, l = threadIdx.x;
  const u64* hq = (const u64*)(h + (size_t)b * HID) + l * 4;
  u64 q[4];
  #pragma unroll
  for (int i = 0; i < 4; ++i)
    q[i] = __hip_atomic_load((const u64*)(hq + i),
                             __ATOMIC_RELAXED, __HIP_MEMORY_SCOPE_AGENT);
  float hv[16];
  #pragma unroll
  for (int i = 0; i < 4; ++i)
    #pragma unroll
    for (int j = 0; j < 4; ++j)
      hv[i * 4 + j] = b2f((u16)(q[i] >> (j * 16)));

  int k0 = l * 16;
  float p[NOUT];
  #pragma unroll
  for (int o = 0; o < NOUT; ++o) {
    p[o] = 0.f;
    #pragma unroll
    for (int j = 0; j < 16; ++j)
      p[o] += hv[j] * Wout[(size_t)o * HID + k0 + j];
  }
  #pragma unroll
  for (int o = 0; o < NOUT; ++o) {
    float v = p[o];
    #pragma unroll
    for (int off = 32; off > 0; off >>= 1) v += __shfl_down(v, off);
    if (l == 0) out[b * NOUT + o] = v + bout[o];
  }
}

// sentinel if workspace too small (distinguishable absmax ~1e9)
__global__ void sentinel_kernel(float* out, int n) {
  int i = blockIdx.x * 256 + threadIdx.x;
  if (i < n) out[i] = 1e9f;
}

extern "C" void kernel_launch(void* const* d_in, const int* in_sizes, int n_in,
                              void* d_out, int out_size, void* d_ws, size_t ws_size,
                              hipStream_t stream) {
  const int*   ids  = (const int*)d_in[0];
  const float* emb  = (const float*)d_in[1];
  const float* Wih  = (const float*)d_in[2];
  const float* Whh  = (const float*)d_in[3];
  const float* bias = (const float*)d_in[4];
  const float* Wout = (const float*)d_in[5];
  const float* bout = (const float*)d_in[6];
  float* out = (float*)d_out;

  if (ws_size < WS_NEED) {
    sentinel_kernel<<<(out_size + 255) / 256, 256, 0, stream>>>(out, out_size);
    return;
  }

  char* ws = (char*)d_ws;
  u16* x   = (u16*)(ws + OFF_X);
  u16* Wr  = (u16*)(ws + OFF_W);
  u16* h0  = (u16*)(ws + OFF_H0);
  u16* h1  = (u16*)(ws + OFF_H1);
  u32* cnt = (u32*)(ws + OFF_CNT);

  hipMemsetAsync(cnt, 0, SZ_CNT, stream);    // barrier counters (every call!)

  embed_kernel<<<SEQ * BATCH, 128, 0, stream>>>(ids, emb, x);
  wpack_kernel<<<GN * NCOL, 256, 0, stream>>>(Wih, Whh, Wr);

  hipFuncSetAttribute((const void*)lstm_kernel,
                      hipFuncAttributeMaxDynamicSharedMemorySize,
                      (int)SMEM_BYTES);
  lstm_kernel<<<NBLK, 256, SMEM_BYTES, stream>>>(x, Wr, bias, h0, h1, cnt);

  // after 512 steps (last write at t=511, odd -> h0), h_last lives in h0
  head_kernel<<<BATCH, 64, 0, stream>>>(h0, Wout, bout, out);
}

// Round 6
// 6118.547 us; speedup vs baseline: 1.6301x; 1.1267x over previous
//
#include <hip/hip_runtime.h>
#include <cstdint>
#include <cstddef>

// ---------------- problem constants ----------------
#define SEQ    512
#define BATCH  128
#define EMB    512
#define HID    1024
#define KTOT   1536   // EMB + HID fused K
#define NOUT   8

// ---------------- decomposition ----------------
#define GN     128    // column-tile blocks over hidden units
#define UPB    8      // hidden units per block  (HID/GN)
#define NCOL   32     // gate columns per block  (4*UPB)
#define NBLK   256    // GN * GM, GM=2 batch halves
#define HBLK   128    // blocks per independent batch-half barrier
#define WPAD   1544   // padded K stride (elements) for LDS W

typedef unsigned short u16;
typedef unsigned int   u32;
typedef unsigned long long u64;
typedef __attribute__((ext_vector_type(8))) __bf16 bf16x8;
typedef __attribute__((ext_vector_type(4))) float  f32x4;
typedef __attribute__((ext_vector_type(4))) float  float4v;
typedef __attribute__((ext_vector_type(4))) u16    u16x4;

// ---------------- workspace layout ----------------
#define OFF_X    0ull
#define SZ_X     ((size_t)SEQ*BATCH*EMB*2)      // 64 MB  bf16 x [S][B][E]
#define OFF_W    (OFF_X + SZ_X)
#define SZ_W     ((size_t)GN*NCOL*KTOT*2)       // 12 MB  bf16 packed weights
#define OFF_H0   (OFF_W + SZ_W)
#define SZ_H     ((size_t)BATCH*HID*2)          // 256 KB bf16 h buffer
#define OFF_H1   (OFF_H0 + SZ_H)
#define OFF_CNT  (OFF_H1 + SZ_H)
#define SZ_CNT   ((size_t)SEQ*32*4)             // 64 KB  cnt[t][half], 64B lines
#define OFF_GO   (OFF_CNT + SZ_CNT)
#define SZ_GO    (256ull)                       // go[half], 64B lines
#define WS_NEED  (OFF_GO + SZ_GO)

#define SMEM_BYTES ((size_t)NCOL*WPAD*2 + 128)

// ---------------- helpers ----------------
__device__ inline u16 f2b(float f) {            // f32 -> bf16 RNE
  uint32_t u = __builtin_bit_cast(uint32_t, f);
  u = u + 0x7FFFu + ((u >> 16) & 1u);
  return (u16)(u >> 16);
}
__device__ inline float b2f(u16 u) {
  uint32_t v = ((uint32_t)u) << 16;
  return __builtin_bit_cast(float, v);
}
__device__ inline float sigm(float x) { return 1.0f / (1.0f + __expf(-x)); }
__device__ inline float tanh_(float x) {
  x = fminf(fmaxf(x, -15.f), 15.f);
  float e = __expf(2.f * x);
  return (e - 1.f) / (e + 1.f);
}
__device__ inline f32x4 mfma16(bf16x8 a, bf16x8 b, f32x4 c) {
  return __builtin_amdgcn_mfma_f32_16x16x32_bf16(a, b, c, 0, 0, 0);
}
struct QQ { u64 x, y; };
__device__ inline bf16x8 qq2v(u64 lo, u64 hi) {
  QQ q; q.x = lo; q.y = hi;
  return __builtin_bit_cast(bf16x8, q);
}

// ---------------- prep: embedding gather -> bf16 x[t][b][e] ----------------
__global__ void embed_kernel(const int* __restrict__ ids,
                             const float* __restrict__ emb,
                             u16* __restrict__ x) {
  int bid = blockIdx.x;            // t*128 + b
  int t = bid >> 7, b = bid & 127;
  int idx = ids[b * SEQ + t];
  const float4v* src = (const float4v*)(emb + (size_t)idx * EMB);
  float4v v = src[threadIdx.x];    // 128 threads x float4 = 512 floats
  u16x4 o;
  o.x = f2b(v.x); o.y = f2b(v.y); o.z = f2b(v.z); o.w = f2b(v.w);
  *(u16x4*)(x + (size_t)bid * EMB + threadIdx.x * 4) = o;
}

// ---------------- prep: pack [W_ih | W_hh] rows, gate-reordered, bf16 --------
// Wr[n][c][k]: block n owns units j0=n*8..n*8+7; c = q*8+u -> row q*1024+n*8+u
__global__ void wpack_kernel(const float* __restrict__ Wih,
                             const float* __restrict__ Whh,
                             u16* __restrict__ Wr) {
  int bid = blockIdx.x;            // n*32 + c
  int c = bid & 31, n = bid >> 5;
  int q = c >> 3, u = c & 7;
  int row = q * HID + n * UPB + u;
  u16* dst = Wr + (size_t)bid * KTOT;
  for (int k = threadIdx.x; k < KTOT; k += 256) {
    float v = (k < EMB) ? Wih[(size_t)row * EMB + k]
                        : Whh[(size_t)row * HID + (k - EMB)];
    dst[k] = f2b(v);
  }
}

// ---------------- persistent LSTM recurrence (fence-free sc1 exchange) ------
__global__ __launch_bounds__(256, 1) void lstm_kernel(
    const u16* __restrict__ x,     // [SEQ][BATCH][EMB] bf16
    const u16* __restrict__ Wr,    // [GN][NCOL][KTOT] bf16
    const float* __restrict__ bias,// [4*HID] f32
    u16* __restrict__ h0,          // [BATCH][HID] bf16 (holds h_last at end)
    u16* __restrict__ h1,          // double buffer B
    u32* __restrict__ cnt,         // [SEQ][2] arrive counters, 64B lines (zeroed)
    u32* __restrict__ go)          // [2] go flags, 64B lines (zeroed)
{
  extern __shared__ char smem[];
  u16* Wl = (u16*)smem;                      // [NCOL][WPAD]

  const int tid  = threadIdx.x;
  const int bid  = blockIdx.x;
  const int n    = bid & (GN - 1);   // column block
  const int mh   = bid >> 7;         // batch half 0/1
  const int lane = tid & 63;
  const int wid  = tid >> 6;         // 4 waves: m-tile id

  // ---- stage W into LDS (once) ----
  const u16* wsrc = Wr + (size_t)n * NCOL * KTOT;
  for (int e = tid * 8; e < NCOL * KTOT; e += 256 * 8) {
    int c = e / KTOT;
    int k = e - c * KTOT;
    *(bf16x8*)&Wl[c * WPAD + k] = *(const bf16x8*)&wsrc[e];
  }
  __syncthreads();

  // ---- MFMA fragment indexing ----
  const int arow = lane & 15;            // A row within 16-tile
  const int kl   = (lane >> 4) * 8;      // k sub-offset within 32-chunk
  const int bg   = mh * 64 + wid * 16 + arow;  // global batch row for A loads
  const int dcol = lane & 15;            // D col within 16-tile
  const int drow = (lane >> 4) * 4;      // D row base within 16-tile

  // ---- elementwise mapping: lane pair (l, l^8) shares unit u = lane&7 ----
  const int  u    = lane & 7;
  const bool lolane = (lane & 8) == 0;
  const int  colu = n * UPB + u;         // global hidden-unit column

  const float bi_ = bias[colu];
  const float bf_ = bias[HID + colu];
  const float bg_ = bias[2 * HID + colu];
  const float bo_ = bias[3 * HID + colu];

  const u16* w0p = &Wl[(dcol) * WPAD + kl];       // n-tile 0 (cols 0..15)
  const u16* w1p = &Wl[(16 + dcol) * WPAD + kl];  // n-tile 1 (cols 16..31)

  float cst[4] = {0.f, 0.f, 0.f, 0.f};   // cell state (redundant in lane pair)

  // ---- barrier lines for this batch half ----
  u32* gol = &go[mh * 16];

  // ---- prefetch x fragments for t=0 ----
  bf16x8 xfrag[16];
  {
    const u16* xr = x + ((size_t)bg) * EMB + kl;
    #pragma unroll
    for (int kc = 0; kc < 16; ++kc) xfrag[kc] = *(const bf16x8*)(xr + kc * 32);
  }

  #pragma unroll 1
  for (int t = 0; t < SEQ; ++t) {
    const u16* hr_buf = (t & 1) ? h1 : h0;
    u16*       hw_buf = (t & 1) ? h0 : h1;
    const u64* hq = (const u64*)(hr_buf + (size_t)bg * HID + kl);

    // ---- issue ALL h loads first: 64 x 8B sc1 loads in flight (bypass L2) --
    bf16x8 hfrag[32];
    if (t > 0) {
      #pragma unroll
      for (int kc = 0; kc < 32; ++kc) {
        u64 lo = __hip_atomic_load((const u64*)(hq + kc * 8),
                                   __ATOMIC_RELAXED, __HIP_MEMORY_SCOPE_AGENT);
        u64 hi = __hip_atomic_load((const u64*)(hq + kc * 8 + 1),
                                   __ATOMIC_RELAXED, __HIP_MEMORY_SCOPE_AGENT);
        hfrag[kc] = qq2v(lo, hi);
      }
    }

    f32x4 acc[2][2];
    #pragma unroll
    for (int i = 0; i < 2; ++i)
      #pragma unroll
      for (int j = 0; j < 2; ++j) acc[i][j] = (f32x4){0.f, 0.f, 0.f, 0.f};

    // ---- x-part MFMAs (independent of h: overlaps h-load latency) ----
    #pragma unroll
    for (int kc = 0; kc < 16; ++kc) {
      bf16x8 w0 = *(const bf16x8*)(w0p + kc * 32);
      bf16x8 w1 = *(const bf16x8*)(w1p + kc * 32);
      acc[kc & 1][0] = mfma16(xfrag[kc], w0, acc[kc & 1][0]);
      acc[kc & 1][1] = mfma16(xfrag[kc], w1, acc[kc & 1][1]);
    }

    // ---- prefetch x for t+1 (completes during h-MFMAs / barrier) ----
    if (t < SEQ - 1) {
      const u16* xr = x + ((size_t)(t + 1) * BATCH + bg) * EMB + kl;
      #pragma unroll
      for (int kc = 0; kc < 16; ++kc) xfrag[kc] = *(const bf16x8*)(xr + kc * 32);
    }

    // ---- h-part MFMAs ----
    if (t > 0) {
      #pragma unroll
      for (int kc = 0; kc < 32; ++kc) {
        bf16x8 w0 = *(const bf16x8*)(w0p + EMB + kc * 32);
        bf16x8 w1 = *(const bf16x8*)(w1p + EMB + kc * 32);
        acc[kc & 1][0] = mfma16(hfrag[kc], w0, acc[kc & 1][0]);
        acc[kc & 1][1] = mfma16(hfrag[kc], w1, acc[kc & 1][1]);
      }
    }

    // ---- gates: tile0 = {i,f}, tile1 = {g,o}; lane^8 holds the partner ----
    f32x4 g0, g1;
    #pragma unroll
    for (int r = 0; r < 4; ++r) {
      g0[r] = acc[0][0][r] + acc[1][0][r];
      g1[r] = acc[0][1][r] + acc[1][1][r];
    }
    f32x4 p0, p1;
    #pragma unroll
    for (int r = 0; r < 4; ++r) {
      p0[r] = __shfl_xor(g0[r], 8);
      p1[r] = __shfl_xor(g1[r], 8);
    }

    float hv4[4];
    #pragma unroll
    for (int r = 0; r < 4; ++r) {
      float iv = (lolane ? g0[r] : p0[r]) + bi_;
      float fv = (lolane ? p0[r] : g0[r]) + bf_;
      float gv = (lolane ? g1[r] : p1[r]) + bg_;
      float ov = (lolane ? p1[r] : g1[r]) + bo_;
      float cn = sigm(fv) * cst[r] + sigm(iv) * tanh_(gv);
      cst[r] = cn;
      hv4[r] = sigm(ov) * tanh_(cn);
    }

    // ---- h stores: pack 2 bf16 via lane^1, write-through u32 sc1 ----
    #pragma unroll
    for (int r = 0; r < 4; ++r) {
      float other = __shfl_xor(hv4[r], 1);          // col partner (u^1)
      bool doStore = (lolane ? (r < 2) : (r >= 2)) && ((u & 1) == 0);
      if (doStore) {
        u32 val = (u32)f2b(hv4[r]) | ((u32)f2b(other) << 16);
        u32* dst = (u32*)&hw_buf[(size_t)(mh * 64 + wid * 16 + drow + r) * HID + colu];
        __hip_atomic_store(dst, val, __ATOMIC_RELAXED, __HIP_MEMORY_SCOPE_AGENT);
      }
    }

    // ---- barrier: RMW-only arrive line; single-writer polled go line ----
    __syncthreads();   // per-wave vmcnt(0) before s_barrier: h stores drained
    if (t == SEQ - 1) break;
    if (tid == 0) {
      u32* cl = &cnt[((size_t)t * 2 + mh) * 16];
      u32 old = __hip_atomic_fetch_add(cl, 1u, __ATOMIC_RELAXED,
                                       __HIP_MEMORY_SCOPE_AGENT);
      if (old == (u32)(HBLK - 1)) {
        // last arriver: everyone's stores are acked; publish go = t+1
        __hip_atomic_store(gol, (u32)(t + 1), __ATOMIC_RELAXED,
                           __HIP_MEMORY_SCOPE_AGENT);
      } else {
        while (__hip_atomic_load(gol, __ATOMIC_RELAXED,
                                 __HIP_MEMORY_SCOPE_AGENT) < (u32)(t + 1)) {
          __builtin_amdgcn_s_sleep(2);
        }
      }
      __asm__ __volatile__("" ::: "memory");
    }
    __syncthreads();
  }
}

// ---------------- classifier head: out = h_last @ W_out^T + b_out ----------
__global__ void head_kernel(const u16* __restrict__ h,
                            const float* __restrict__ Wout,
                            const float* __restrict__ bout,
                            float* __restrict__ out) {
  int b = blockIdx.x, l = threadIdx.x;
  const u64* hq = (const u64*)(h + (size_t)b * HID) + l * 4;
  u64 q[4];
  #pragma unroll
  for (int i = 0; i < 4; ++i)
    q[i] = __hip_atomic_load((const u64*)(hq + i),
                             __ATOMIC_RELAXED, __HIP_MEMORY_SCOPE_AGENT);
  float hv[16];
  #pragma unroll
  for (int i = 0; i < 4; ++i)
    #pragma unroll
    for (int j = 0; j < 4; ++j)
      hv[i * 4 + j] = b2f((u16)(q[i] >> (j * 16)));

  int k0 = l * 16;
  float p[NOUT];
  #pragma unroll
  for (int o = 0; o < NOUT; ++o) {
    p[o] = 0.f;
    #pragma unroll
    for (int j = 0; j < 16; ++j)
      p[o] += hv[j] * Wout[(size_t)o * HID + k0 + j];
  }
  #pragma unroll
  for (int o = 0; o < NOUT; ++o) {
    float v = p[o];
    #pragma unroll
    for (int off = 32; off > 0; off >>= 1) v += __shfl_down(v, off);
    if (l == 0) out[b * NOUT + o] = v + bout[o];
  }
}

// sentinel if workspace too small (distinguishable absmax ~1e9)
__global__ void sentinel_kernel(float* out, int n) {
  int i = blockIdx.x * 256 + threadIdx.x;
  if (i < n) out[i] = 1e9f;
}

extern "C" void kernel_launch(void* const* d_in, const int* in_sizes, int n_in,
                              void* d_out, int out_size, void* d_ws, size_t ws_size,
                              hipStream_t stream) {
  const int*   ids  = (const int*)d_in[0];
  const float* emb  = (const float*)d_in[1];
  const float* Wih  = (const float*)d_in[2];
  const float* Whh  = (const float*)d_in[3];
  const float* bias = (const float*)d_in[4];
  const float* Wout = (const float*)d_in[5];
  const float* bout = (const float*)d_in[6];
  float* out = (float*)d_out;

  if (ws_size < WS_NEED) {
    sentinel_kernel<<<(out_size + 255) / 256, 256, 0, stream>>>(out, out_size);
    return;
  }

  char* ws = (char*)d_ws;
  u16* x   = (u16*)(ws + OFF_X);
  u16* Wr  = (u16*)(ws + OFF_W);
  u16* h0  = (u16*)(ws + OFF_H0);
  u16* h1  = (u16*)(ws + OFF_H1);
  u32* cnt = (u32*)(ws + OFF_CNT);
  u32* go  = (u32*)(ws + OFF_GO);

  hipMemsetAsync(cnt, 0, SZ_CNT + SZ_GO, stream);  // cnt+go contiguous (every call!)

  embed_kernel<<<SEQ * BATCH, 128, 0, stream>>>(ids, emb, x);
  wpack_kernel<<<GN * NCOL, 256, 0, stream>>>(Wih, Whh, Wr);

  hipFuncSetAttribute((const void*)lstm_kernel,
                      hipFuncAttributeMaxDynamicSharedMemorySize,
                      (int)SMEM_BYTES);
  lstm_kernel<<<NBLK, 256, SMEM_BYTES, stream>>>(x, Wr, bias, h0, h1, cnt, go);

  // after 512 steps (last write at t=511, odd -> h0), h_last lives in h0
  head_kernel<<<BATCH, 64, 0, stream>>>(h0, Wout, bout, out);
}